// Round 1
// baseline (208.762 us; speedup 1.0000x reference)
//
#include <hip/hip_runtime.h>

#pragma clang fp contract(off)

#define TOLD 60000
#define TNEW 60000
#define NVERT 30000
#define MAXSTEPS 300
#define THSZ 131072                  // tet-key hash slots (load 0.46)
#define FHSZ 524288                  // face-key hash slots (load 0.46)
#define EMPTY64 0xFFFFFFFFFFFFFFFFULL

struct P {
  const unsigned int* rawNew;        // new_indices raw bytes (int32 or int64, detected)
  const unsigned int* rawOld;        // old_indices raw bytes
  const float* occ;                  // old_cc  (TOLD,3)
  const float* ncc;                  // new_cc  (TNEW,3)
  const float* verts;                // vertex_positions (NVERT,3)
  float* out;                        // cands | weights | density, each (TNEW,5) flat
  unsigned long long* tkeys;         // tet hash keys
  unsigned long long* ftab;          // face hash (packed key<<18 | tet*4+local)
  int* counters;                     // [0]=n_walk [1]=cntA [2]=cntB [3]=is64
  int* tvals;                        // tet hash values (max tet id)
  int* idxNew; int* idxOld;          // int32-normalized indices
  int* nbr;                          // neighbors (TOLD,4), -1 = none
  int* prio;                         // per-vertex max(vi*TOLD+t)
  int* matched;                      // per new tet: old tet id or -1
  int* cur; int* rem; int* act;      // walk state
  int* degen;                        // per old tet degenerate flag
  int* listA; int* listB;            // active-list ping-pong
  float* Tinv;                       // (TOLD,9) row-major inverse
  float* v0c;                        // (TOLD,3) first vertex
  float* cold;                       // (TOLD,3) old centroids
  float* oel;                        // (TOLD,) min edge length
  float* cnew;                       // (TNEW,3) new centroids
  float* nel;                        // (TNEW,) min edge length
};

__device__ __forceinline__ unsigned hash64(unsigned long long k){
  k ^= k >> 33; k *= 0xff51afd7ed558ccdULL;
  k ^= k >> 33; k *= 0xc4ceb9fe1a85ec53ULL;
  k ^= k >> 33;
  return (unsigned)k;
}
__device__ __forceinline__ void cswap(int& a, int& b){ if (a > b){ int t = a; a = b; b = t; } }

__global__ void k_init(P p){
  int i = blockIdx.x * blockDim.x + threadIdx.x;
  if (i < 64) p.counters[i] = 0;
  if (i < THSZ){ p.tkeys[i] = EMPTY64; p.tvals[i] = -1; }
  if (i < FHSZ) p.ftab[i] = EMPTY64;
  if (i < TOLD * 4) p.nbr[i] = -1;
  if (i < NVERT) p.prio[i] = -1;
}

// int64 buffers (values < 2^31, nonneg) have zero high words at odd u32 positions;
// int32 buffers never do (odd flat positions are cols 1/3, values >= 1).
__global__ void k_detect(P p){
  if (blockIdx.x == 0 && threadIdx.x == 0){
    int is64 = 1;
    for (int k = 0; k < 64; ++k) if (p.rawNew[2 * k + 1] != 0u){ is64 = 0; break; }
    p.counters[3] = is64;
  }
}

__global__ void k_convert(P p){
  int i = blockIdx.x * blockDim.x + threadIdx.x;
  int is64 = p.counters[3];
  if (i < TNEW * 4){
    p.idxNew[i] = is64 ? (int)((const long long*)p.rawNew)[i] : ((const int*)p.rawNew)[i];
  } else if (i < TNEW * 4 + TOLD * 4){
    int j = i - TNEW * 4;
    p.idxOld[j] = is64 ? (int)((const long long*)p.rawOld)[j] : ((const int*)p.rawOld)[j];
  }
}

__device__ __forceinline__ void face_insert(unsigned long long* ftab, int* nbr,
                                            unsigned long long fkey, int t, int l){
  unsigned long long mine = (fkey << 18) | (unsigned long long)(t * 4 + l);
  unsigned slot = hash64(fkey) & (FHSZ - 1);
  while (true){
    unsigned long long prev = atomicCAS(&ftab[slot], EMPTY64, mine);
    if (prev == EMPTY64) return;                       // first holder of this face
    if ((prev >> 18) == fkey){                         // partner found: link both ways
      int oid = (int)(prev & 0x3FFFFULL);
      int ot = oid >> 2, ol = oid & 3;
      nbr[t * 4 + l] = ot;
      nbr[ot * 4 + ol] = t;
      return;
    }
    slot = (slot + 1) & (FHSZ - 1);
  }
}

__device__ __forceinline__ float min_edge(const float* __restrict__ verts,
                                          int i0, int i1, int i2, int i3){
  float q[4][3];
  int iv[4] = {i0, i1, i2, i3};
  for (int k = 0; k < 4; ++k){
    q[k][0] = verts[iv[k] * 3 + 0];
    q[k][1] = verts[iv[k] * 3 + 1];
    q[k][2] = verts[iv[k] * 3 + 2];
  }
  const int ea[6] = {0, 0, 0, 1, 1, 2};
  const int eb[6] = {1, 2, 3, 2, 3, 3};
  float m = 3.402823466e+38f;
  for (int e = 0; e < 6; ++e){
    float dx = q[ea[e]][0] - q[eb[e]][0];
    float dy = q[ea[e]][1] - q[eb[e]][1];
    float dz = q[ea[e]][2] - q[eb[e]][2];
    float d = sqrtf((dx * dx + dy * dy) + dz * dz);
    m = fminf(m, d);
  }
  return m;
}

__global__ void k_old_setup(P p){
  int t = blockIdx.x * blockDim.x + threadIdx.x;
  if (t >= TOLD) return;
  int i0 = p.idxOld[t * 4 + 0], i1 = p.idxOld[t * 4 + 1];
  int i2 = p.idxOld[t * 4 + 2], i3 = p.idxOld[t * 4 + 3];

  // tet key (sorted) -> hash insert, duplicate keys keep MAX tet id (matches
  // stable argsort + searchsorted 'right' - 1 in the reference)
  int s0 = i0, s1 = i1, s2 = i2, s3 = i3;
  cswap(s0, s1); cswap(s2, s3); cswap(s0, s2); cswap(s1, s3); cswap(s1, s2);
  unsigned long long key =
      (unsigned long long)((((long long)s0 * NVERT + s1) * NVERT + s2) * NVERT + s3);
  {
    unsigned slot = hash64(key) & (THSZ - 1);
    while (true){
      unsigned long long prev = atomicCAS(&p.tkeys[slot], EMPTY64, key);
      if (prev == EMPTY64 || prev == key){ atomicMax(&p.tvals[slot], t); break; }
      slot = (slot + 1) & (THSZ - 1);
    }
  }
  // vertex -> tet priority
  atomicMax(&p.prio[i0], 0 * TOLD + t);
  atomicMax(&p.prio[i1], 1 * TOLD + t);
  atomicMax(&p.prio[i2], 2 * TOLD + t);
  atomicMax(&p.prio[i3], 3 * TOLD + t);

  // faces (sorted triples) -> mutual neighbor link
  const int FO[4][3] = {{1, 2, 3}, {0, 2, 3}, {0, 1, 3}, {0, 1, 2}};
  int iv[4] = {i0, i1, i2, i3};
  for (int l = 0; l < 4; ++l){
    int a = iv[FO[l][0]], b = iv[FO[l][1]], c = iv[FO[l][2]];
    cswap(a, b); cswap(a, c); cswap(b, c);
    unsigned long long fk = (unsigned long long)(((long long)a * NVERT + b) * NVERT + c);
    face_insert(p.ftab, p.nbr, fk, t, l);
  }

  // geometry: Tinv (adjugate/det), centroid, v0, min edge length
  float q0x = p.verts[i0 * 3 + 0], q0y = p.verts[i0 * 3 + 1], q0z = p.verts[i0 * 3 + 2];
  float q1x = p.verts[i1 * 3 + 0], q1y = p.verts[i1 * 3 + 1], q1z = p.verts[i1 * 3 + 2];
  float q2x = p.verts[i2 * 3 + 0], q2y = p.verts[i2 * 3 + 1], q2z = p.verts[i2 * 3 + 2];
  float q3x = p.verts[i3 * 3 + 0], q3y = p.verts[i3 * 3 + 1], q3z = p.verts[i3 * 3 + 2];
  float e1x = q1x - q0x, e1y = q1y - q0y, e1z = q1z - q0z;
  float e2x = q2x - q0x, e2y = q2y - q0y, e2z = q2z - q0z;
  float e3x = q3x - q0x, e3y = q3y - q0y, e3z = q3z - q0z;
  float c23x = e2y * e3z - e2z * e3y;
  float c23y = e2z * e3x - e2x * e3z;
  float c23z = e2x * e3y - e2y * e3x;
  float det = e1x * c23x + e1y * c23y + e1z * c23z;
  int dg = (fabsf(det) < 1e-10f) ? 1 : 0;
  p.degen[t] = dg;
  float M[9];
  if (dg){
    M[0] = 1.f; M[1] = 0.f; M[2] = 0.f;
    M[3] = 0.f; M[4] = 1.f; M[5] = 0.f;
    M[6] = 0.f; M[7] = 0.f; M[8] = 1.f;
  } else {
    float inv = 1.0f / det;
    float c31x = e3y * e1z - e3z * e1y;
    float c31y = e3z * e1x - e3x * e1z;
    float c31z = e3x * e1y - e3y * e1x;
    float c12x = e1y * e2z - e1z * e2y;
    float c12y = e1z * e2x - e1x * e2z;
    float c12z = e1x * e2y - e1y * e2x;
    M[0] = c23x * inv; M[1] = c23y * inv; M[2] = c23z * inv;
    M[3] = c31x * inv; M[4] = c31y * inv; M[5] = c31z * inv;
    M[6] = c12x * inv; M[7] = c12y * inv; M[8] = c12z * inv;
  }
  for (int k = 0; k < 9; ++k) p.Tinv[t * 9 + k] = M[k];
  p.v0c[t * 3 + 0] = q0x; p.v0c[t * 3 + 1] = q0y; p.v0c[t * 3 + 2] = q0z;
  p.cold[t * 3 + 0] = (((q0x + q1x) + q2x) + q3x) * 0.25f;
  p.cold[t * 3 + 1] = (((q0y + q1y) + q2y) + q3y) * 0.25f;
  p.cold[t * 3 + 2] = (((q0z + q1z) + q2z) + q3z) * 0.25f;
  p.oel[t] = min_edge(p.verts, i0, i1, i2, i3);
}

__global__ void k_degen(P p){
  int t = blockIdx.x * blockDim.x + threadIdx.x;
  if (t >= TOLD) return;
  if (p.degen[t]){
    p.nbr[t * 4 + 0] = -1; p.nbr[t * 4 + 1] = -1;
    p.nbr[t * 4 + 2] = -1; p.nbr[t * 4 + 3] = -1;
  }
}

__global__ void k_new_setup(P p){
  int n = blockIdx.x * blockDim.x + threadIdx.x;
  if (n >= TNEW) return;
  int i0 = p.idxNew[n * 4 + 0], i1 = p.idxNew[n * 4 + 1];
  int i2 = p.idxNew[n * 4 + 2], i3 = p.idxNew[n * 4 + 3];
  int s0 = i0, s1 = i1, s2 = i2, s3 = i3;
  cswap(s0, s1); cswap(s2, s3); cswap(s0, s2); cswap(s1, s3); cswap(s1, s2);
  unsigned long long key =
      (unsigned long long)((((long long)s0 * NVERT + s1) * NVERT + s2) * NVERT + s3);
  int m = -1;
  {
    unsigned slot = hash64(key) & (THSZ - 1);
    while (true){
      unsigned long long k = p.tkeys[slot];
      if (k == EMPTY64) break;
      if (k == key){ m = p.tvals[slot]; break; }
      slot = (slot + 1) & (THSZ - 1);
    }
  }
  p.matched[n] = m;
  float q0x = p.verts[i0 * 3 + 0], q0y = p.verts[i0 * 3 + 1], q0z = p.verts[i0 * 3 + 2];
  float q1x = p.verts[i1 * 3 + 0], q1y = p.verts[i1 * 3 + 1], q1z = p.verts[i1 * 3 + 2];
  float q2x = p.verts[i2 * 3 + 0], q2y = p.verts[i2 * 3 + 1], q2z = p.verts[i2 * 3 + 2];
  float q3x = p.verts[i3 * 3 + 0], q3y = p.verts[i3 * 3 + 1], q3z = p.verts[i3 * 3 + 2];
  p.cnew[n * 3 + 0] = (((q0x + q1x) + q2x) + q3x) * 0.25f;
  p.cnew[n * 3 + 1] = (((q0y + q1y) + q2y) + q3y) * 0.25f;
  p.cnew[n * 3 + 2] = (((q0z + q1z) + q2z) + q3z) * 0.25f;
  p.nel[n] = min_edge(p.verts, i0, i1, i2, i3);
  int pr = p.prio[i0];
  int seed = (pr >= 0) ? (pr % TOLD) : 0;
  p.cur[n] = seed;
  p.rem[n] = seed;
  int a = (m < 0) ? 1 : 0;
  p.act[n] = a;
  if (a) atomicAdd(&p.counters[0], 1);
}

// One reference while-loop body for walker n. Returns true if still active.
__device__ __forceinline__ bool walk_step(const P& p, int n){
  int c = p.cur[n];
  float rx = p.cnew[n * 3 + 0] - p.v0c[c * 3 + 0];
  float ry = p.cnew[n * 3 + 1] - p.v0c[c * 3 + 1];
  float rz = p.cnew[n * 3 + 2] - p.v0c[c * 3 + 2];
  const float* M = &p.Tinv[c * 9];
  float b0 = M[0] * rx + M[1] * ry + M[2] * rz;
  float b1 = M[3] * rx + M[4] * ry + M[5] * rz;
  float b2 = M[6] * rx + M[7] * ry + M[8] * rz;
  float a0 = 1.0f - (b0 + b1 + b2);
  float ab[4] = {a0, b0, b1, b2};
  int amin = 0; float mn = ab[0];
  for (int j = 1; j < 4; ++j){ if (ab[j] < mn){ mn = ab[j]; amin = j; } }
  if (mn >= -0.0001f){ p.rem[n] = c; p.act[n] = 0; return false; }  // converged
  int nb = p.nbr[c * 4 + amin];
  if (nb < 0){ p.rem[n] = c; p.act[n] = 0; return false; }          // boundary
  p.cur[n] = nb;
  return true;
}

__global__ void k_walk1(P p){
  int n = blockIdx.x * blockDim.x + threadIdx.x;
  if (n >= TNEW) return;
  if (!p.act[n]) return;
  int nw = p.counters[0];
  int thr = max(100, nw / 1000);
  if (nw < thr) return;                 // reference loop never runs
  if (walk_step(p, n)){
    int pos = atomicAdd(&p.counters[1], 1);
    p.listA[pos] = n;
  }
}

__global__ void __launch_bounds__(1024) k_persist(P p){
  __shared__ int s_cnt;
  int thr = max(100, p.counters[0] / 1000);
  if (threadIdx.x == 0) s_cnt = atomicAdd(&p.counters[1], 0);
  __syncthreads();
  int count = s_cnt;
  int use_a = 1;
  int step = 1;                          // k_walk1 performed body #1 (if it ran)
  while (step < MAXSTEPS && count >= thr){
    int* curL = use_a ? p.listA : p.listB;
    int* nxtL = use_a ? p.listB : p.listA;
    int* nxtC = use_a ? &p.counters[2] : &p.counters[1];
    int* curC = use_a ? &p.counters[1] : &p.counters[2];
    for (int i = threadIdx.x; i < count; i += blockDim.x){
      int n = curL[i];
      if (walk_step(p, n)){
        int pos = atomicAdd(nxtC, 1);
        nxtL[pos] = n;
      }
    }
    __syncthreads();
    if (threadIdx.x == 0){
      s_cnt = atomicAdd(nxtC, 0);
      atomicExch(curC, 0);               // ready for reuse next ping-pong
    }
    __syncthreads();
    count = s_cnt;
    use_a ^= 1;
    ++step;
  }
}

// Nearest-old-centroid fallback for still-active walkers.
// Reference tie-break (strict < across chunks, argmin within chunk) == first
// index achieving the global float min.
__global__ void k_fallback(P p){
  __shared__ float sd[256];
  __shared__ int si[256];
  for (int n = blockIdx.x; n < TNEW; n += gridDim.x){
    if (p.act[n] == 0) continue;                     // uniform per block
    float cx = p.cnew[n * 3 + 0], cy = p.cnew[n * 3 + 1], cz = p.cnew[n * 3 + 2];
    float p2 = (cx * cx + cy * cy) + cz * cz;
    float bd = 3.402823466e+38f; int bi = 0;
    for (int j = threadIdx.x; j < TOLD; j += 256){
      float ox = p.cold[j * 3 + 0], oy = p.cold[j * 3 + 1], oz = p.cold[j * 3 + 2];
      float dot = (cx * ox + cy * oy) + cz * oz;
      float c2 = (ox * ox + oy * oy) + oz * oz;
      float d = (p2 - 2.0f * dot) + c2;
      if (d < bd || (d == bd && j < bi)){ bd = d; bi = j; }
    }
    sd[threadIdx.x] = bd; si[threadIdx.x] = bi;
    __syncthreads();
    for (int s = 128; s > 0; s >>= 1){
      if ((int)threadIdx.x < s){
        float od = sd[threadIdx.x + s]; int oi = si[threadIdx.x + s];
        if (od < sd[threadIdx.x] || (od == sd[threadIdx.x] && oi < si[threadIdx.x])){
          sd[threadIdx.x] = od; si[threadIdx.x] = oi;
        }
      }
      __syncthreads();
    }
    if (threadIdx.x == 0){
      int r = si[0];
      if (r < 0) r = 0; if (r > TOLD - 1) r = TOLD - 1;
      p.rem[n] = r;
    }
    __syncthreads();
  }
}

__global__ void k_assemble(P p){
  int n = blockIdx.x * blockDim.x + threadIdx.x;
  if (n >= TNEW) return;
  int m = p.matched[n];
  int remap = (m >= 0) ? m : p.rem[n];
  int cds[5];
  cds[0] = remap;
  for (int l = 0; l < 4; ++l){
    int fb = p.nbr[remap * 4 + l];
    cds[1 + l] = (fb >= 0) ? fb : remap;
  }
  if (m >= 0){ for (int c = 0; c < 5; ++c) cds[c] = m; }
  int ni0 = p.idxNew[n * 4 + 0], ni1 = p.idxNew[n * 4 + 1];
  int ni2 = p.idxNew[n * 4 + 2], ni3 = p.idxNew[n * 4 + 3];
  float nc0 = p.ncc[n * 3 + 0], nc1 = p.ncc[n * 3 + 1], nc2 = p.ncc[n * 3 + 2];
  float raws[5]; float rsum = 0.0f;
  for (int c = 0; c < 5; ++c){
    int ct = cds[c];
    int ov = 0;
    for (int k = 0; k < 4; ++k){
      int cv = p.idxOld[ct * 4 + k];
      ov += (cv == ni0 || cv == ni1 || cv == ni2 || cv == ni3) ? 1 : 0;
    }
    float d0 = p.occ[ct * 3 + 0] - nc0;
    float d1 = p.occ[ct * 3 + 1] - nc1;
    float d2 = p.occ[ct * 3 + 2] - nc2;
    float ccd2 = (d0 * d0 + d1 * d1) + d2 * d2;
    float raw = expf((float)ov * 2.0f) / (ccd2 + 1e-8f);
    raws[c] = raw; rsum += raw;
  }
  float nelv = fmaxf(p.nel[n], 1e-8f);
  for (int c = 0; c < 5; ++c){
    p.out[n * 5 + c] = (float)cds[c];
    p.out[TNEW * 5 + n * 5 + c] = raws[c] / rsum;
    float ds = p.oel[cds[c]] / nelv;
    ds = fminf(fmaxf(ds, 0.1f), 10.0f);
    p.out[2 * TNEW * 5 + n * 5 + c] = ds;
  }
}

extern "C" void kernel_launch(void* const* d_in, const int* in_sizes, int n_in,
                              void* d_out, int out_size, void* d_ws, size_t ws_size,
                              hipStream_t stream) {
  char* w = (char*)d_ws;
  P p;
  p.rawNew = (const unsigned int*)d_in[0];
  p.rawOld = (const unsigned int*)d_in[1];
  p.occ    = (const float*)d_in[2];
  p.ncc    = (const float*)d_in[3];
  p.verts  = (const float*)d_in[4];
  p.out    = (float*)d_out;
  // workspace layout (u64 tables first for alignment); total ~15.25 MB
  p.tkeys    = (unsigned long long*)(w + 0);          // 131072*8 = 1,048,576
  p.ftab     = (unsigned long long*)(w + 1048576);    // 524288*8 = 4,194,304
  p.counters = (int*)(w + 5242880);                   // 256
  p.tvals    = (int*)(w + 5243136);                   // 524,288
  p.idxNew   = (int*)(w + 5767424);                   // 960,000
  p.idxOld   = (int*)(w + 6727424);                   // 960,000
  p.nbr      = (int*)(w + 7687424);                   // 960,000
  p.prio     = (int*)(w + 8647424);                   // 120,000
  p.matched  = (int*)(w + 8767424);                   // 240,000
  p.cur      = (int*)(w + 9007424);                   // 240,000
  p.rem      = (int*)(w + 9247424);                   // 240,000
  p.act      = (int*)(w + 9487424);                   // 240,000
  p.degen    = (int*)(w + 9727424);                   // 240,000
  p.listA    = (int*)(w + 9967424);                   // 240,000
  p.listB    = (int*)(w + 10207424);                  // 240,000
  p.Tinv     = (float*)(w + 10447424);                // 2,160,000
  p.v0c      = (float*)(w + 12607424);                // 720,000
  p.cold     = (float*)(w + 13327424);                // 720,000
  p.oel      = (float*)(w + 14047424);                // 240,000
  p.cnew     = (float*)(w + 14287424);                // 720,000
  p.nel      = (float*)(w + 15007424);                // 240,000

  dim3 B(256);
  hipLaunchKernelGGL(k_init,      dim3(FHSZ / 256), B, 0, stream, p);
  hipLaunchKernelGGL(k_detect,    dim3(1), dim3(64), 0, stream, p);
  hipLaunchKernelGGL(k_convert,   dim3((TNEW * 4 + TOLD * 4) / 256), B, 0, stream, p);
  hipLaunchKernelGGL(k_old_setup, dim3((TOLD + 255) / 256), B, 0, stream, p);
  hipLaunchKernelGGL(k_degen,     dim3((TOLD + 255) / 256), B, 0, stream, p);
  hipLaunchKernelGGL(k_new_setup, dim3((TNEW + 255) / 256), B, 0, stream, p);
  hipLaunchKernelGGL(k_walk1,     dim3((TNEW + 255) / 256), B, 0, stream, p);
  hipLaunchKernelGGL(k_persist,   dim3(1), dim3(1024), 0, stream, p);
  hipLaunchKernelGGL(k_fallback,  dim3(240), B, 0, stream, p);
  hipLaunchKernelGGL(k_assemble,  dim3((TNEW + 255) / 256), B, 0, stream, p);
}

// Round 2
// 153.550 us; speedup vs baseline: 1.3596x; 1.3596x over previous
//
#include <hip/hip_runtime.h>

#pragma clang fp contract(off)

#define TOLD 60000
#define TNEW 60000
#define NVERT 30000
#define MAXSTEPS 300
#define THSZ 131072                  // tet-key hash slots (load 0.46)
#define FHSZ 524288                  // face-key hash slots (load 0.46)
#define EMPTY64 0xFFFFFFFFFFFFFFFFULL

// workspace layout: [0xFF-init region][zero-init region][uninitialized]
#define OFF_TKEYS    0u              // 131072*8 = 1,048,576
#define OFF_FTAB     1048576u        // 524288*8 = 4,194,304
#define OFF_TVALS    5242880u        // 131072*4 = 524,288
#define OFF_NBR      5767168u        // 240000*4 = 960,000
#define OFF_PRIO     6727168u        // 30000*4  = 120,000
#define FF_BYTES     6847168u        // end of 0xFF region
#define OFF_CNT      6847168u        // 256 B zeroed
#define OFF_IDXNEW   6847424u        // 960,000
#define OFF_IDXOLD   7807424u        // 960,000
#define OFF_MATCHED  8767424u        // 240,000
#define OFF_CUR      9007424u        // 240,000
#define OFF_REM      9247424u        // 240,000
#define OFF_DEGEN    9487424u        // 240,000
#define OFF_LISTA    9727424u        // 240,000
#define OFF_LISTB    9967424u        // 240,000
#define OFF_TINV     10207424u       // 2,160,000
#define OFF_V0C      12367424u       // 720,000
#define OFF_COLD     13087424u       // 720,000
#define OFF_OEL      13807424u       // 240,000
#define OFF_CNEW     14047424u       // 720,000
#define OFF_NEL      14767424u       // 240,000  -> total 15,007,424 B

struct P {
  const unsigned int* rawNew;        // new_indices raw (int32 or int64, detected per-block)
  const unsigned int* rawOld;        // old_indices raw
  const float* occ;                  // old_cc  (TOLD,3)
  const float* ncc;                  // new_cc  (TNEW,3)
  const float* verts;                // vertex_positions (NVERT,3)
  float* out;                        // cands | weights | density, each (TNEW,5) flat
  unsigned long long* tkeys;         // tet hash keys
  unsigned long long* ftab;          // face hash (key<<18 | tet*4+local)
  int* counters;                     // [0]=n_walk [1]=cntA [2]=cntB [4]=finalCnt [5]=finalList
  int* tvals;                        // tet hash values (max tet id)
  int* idxNew; int* idxOld;          // int32-normalized indices
  int* nbr;                          // neighbors (TOLD,4), -1 = none
  int* prio;                         // per-vertex max(vi*TOLD+t)
  int* matched;                      // per new tet: old tet id or -1
  int* cur; int* rem;                // walk state
  int* degen;                        // per old tet degenerate flag
  int* listA; int* listB;            // active-list ping-pong
  float* Tinv;                       // (TOLD,9) row-major inverse
  float* v0c;                        // (TOLD,3) first vertex
  float* cold;                       // (TOLD,3) old centroids
  float* oel;                        // (TOLD,) min edge length
  float* cnew;                       // (TNEW,3) new centroids
  float* nel;                        // (TNEW,) min edge length
};

__device__ __forceinline__ unsigned hash64(unsigned long long k){
  k ^= k >> 33; k *= 0xff51afd7ed558ccdULL;
  k ^= k >> 33; k *= 0xc4ceb9fe1a85ec53ULL;
  k ^= k >> 33;
  return (unsigned)k;
}
__device__ __forceinline__ void cswap(int& a, int& b){ if (a > b){ int t = a; a = b; b = t; } }

// int64 buffers (values in [0,2^31), nonneg) have zero high words at odd u32
// positions; int32 buffers have col1 >= 1 at flat position 1. Deterministic,
// identical across all blocks — no cross-block dependency needed.
__device__ __forceinline__ int detect64(const unsigned int* raw){
  unsigned acc = 0;
  const uint4* r4 = (const uint4*)raw;
  #pragma unroll
  for (int k = 0; k < 32; ++k){ uint4 v = r4[k]; acc |= (v.y | v.w); }
  return acc == 0u;
}
__device__ __forceinline__ int ld_idx(const unsigned int* raw, int is64, int i){
  return is64 ? (int)((const long long*)raw)[i] : ((const int*)raw)[i];
}

__device__ __forceinline__ void face_insert(unsigned long long* ftab, int* nbr,
                                            unsigned long long fkey, int t, int l){
  unsigned long long mine = (fkey << 18) | (unsigned long long)(t * 4 + l);
  unsigned slot = hash64(fkey) & (FHSZ - 1);
  while (true){
    unsigned long long prev = atomicCAS(&ftab[slot], EMPTY64, mine);
    if (prev == EMPTY64) return;                       // first holder of this face
    if ((prev >> 18) == fkey){                         // partner: link both ways
      int oid = (int)(prev & 0x3FFFFULL);
      nbr[t * 4 + l] = oid >> 2;
      nbr[oid] = t;
      return;
    }
    slot = (slot + 1) & (FHSZ - 1);
  }
}

__device__ __forceinline__ float min_edge(const float* __restrict__ verts,
                                          int i0, int i1, int i2, int i3){
  float q[4][3];
  int iv[4] = {i0, i1, i2, i3};
  for (int k = 0; k < 4; ++k){
    q[k][0] = verts[iv[k] * 3 + 0];
    q[k][1] = verts[iv[k] * 3 + 1];
    q[k][2] = verts[iv[k] * 3 + 2];
  }
  const int ea[6] = {0, 0, 0, 1, 1, 2};
  const int eb[6] = {1, 2, 3, 2, 3, 3};
  float m = 3.402823466e+38f;
  for (int e = 0; e < 6; ++e){
    float dx = q[ea[e]][0] - q[eb[e]][0];
    float dy = q[ea[e]][1] - q[eb[e]][1];
    float dz = q[ea[e]][2] - q[eb[e]][2];
    float d = sqrtf((dx * dx + dy * dy) + dz * dz);
    m = fminf(m, d);
  }
  return m;
}

__global__ void k_old_setup(P p){
  int t = blockIdx.x * blockDim.x + threadIdx.x;
  if (t >= TOLD) return;
  int is64 = detect64(p.rawOld);
  int i0 = ld_idx(p.rawOld, is64, t * 4 + 0);
  int i1 = ld_idx(p.rawOld, is64, t * 4 + 1);
  int i2 = ld_idx(p.rawOld, is64, t * 4 + 2);
  int i3 = ld_idx(p.rawOld, is64, t * 4 + 3);
  p.idxOld[t * 4 + 0] = i0; p.idxOld[t * 4 + 1] = i1;
  p.idxOld[t * 4 + 2] = i2; p.idxOld[t * 4 + 3] = i3;

  // tet key (sorted) -> hash insert; duplicate keys keep MAX tet id (matches
  // stable argsort + searchsorted('right')-1 in the reference)
  int s0 = i0, s1 = i1, s2 = i2, s3 = i3;
  cswap(s0, s1); cswap(s2, s3); cswap(s0, s2); cswap(s1, s3); cswap(s1, s2);
  unsigned long long key =
      (unsigned long long)((((long long)s0 * NVERT + s1) * NVERT + s2) * NVERT + s3);
  {
    unsigned slot = hash64(key) & (THSZ - 1);
    while (true){
      unsigned long long prev = atomicCAS(&p.tkeys[slot], EMPTY64, key);
      if (prev == EMPTY64 || prev == key){ atomicMax(&p.tvals[slot], t); break; }
      slot = (slot + 1) & (THSZ - 1);
    }
  }
  atomicMax(&p.prio[i0], 0 * TOLD + t);
  atomicMax(&p.prio[i1], 1 * TOLD + t);
  atomicMax(&p.prio[i2], 2 * TOLD + t);
  atomicMax(&p.prio[i3], 3 * TOLD + t);

  // faces (sorted triples) -> mutual neighbor link
  const int FO[4][3] = {{1, 2, 3}, {0, 2, 3}, {0, 1, 3}, {0, 1, 2}};
  int iv[4] = {i0, i1, i2, i3};
  for (int l = 0; l < 4; ++l){
    int a = iv[FO[l][0]], b = iv[FO[l][1]], c = iv[FO[l][2]];
    cswap(a, b); cswap(a, c); cswap(b, c);
    unsigned long long fk = (unsigned long long)(((long long)a * NVERT + b) * NVERT + c);
    face_insert(p.ftab, p.nbr, fk, t, l);
  }

  // geometry: Tinv (adjugate/det), v0, centroid, min edge length
  float q0x = p.verts[i0 * 3 + 0], q0y = p.verts[i0 * 3 + 1], q0z = p.verts[i0 * 3 + 2];
  float q1x = p.verts[i1 * 3 + 0], q1y = p.verts[i1 * 3 + 1], q1z = p.verts[i1 * 3 + 2];
  float q2x = p.verts[i2 * 3 + 0], q2y = p.verts[i2 * 3 + 1], q2z = p.verts[i2 * 3 + 2];
  float q3x = p.verts[i3 * 3 + 0], q3y = p.verts[i3 * 3 + 1], q3z = p.verts[i3 * 3 + 2];
  float e1x = q1x - q0x, e1y = q1y - q0y, e1z = q1z - q0z;
  float e2x = q2x - q0x, e2y = q2y - q0y, e2z = q2z - q0z;
  float e3x = q3x - q0x, e3y = q3y - q0y, e3z = q3z - q0z;
  float c23x = e2y * e3z - e2z * e3y;
  float c23y = e2z * e3x - e2x * e3z;
  float c23z = e2x * e3y - e2y * e3x;
  float det = e1x * c23x + e1y * c23y + e1z * c23z;
  int dg = (fabsf(det) < 1e-10f) ? 1 : 0;
  p.degen[t] = dg;
  float M[9];
  if (dg){
    M[0] = 1.f; M[1] = 0.f; M[2] = 0.f;
    M[3] = 0.f; M[4] = 1.f; M[5] = 0.f;
    M[6] = 0.f; M[7] = 0.f; M[8] = 1.f;
  } else {
    float inv = 1.0f / det;
    float c31x = e3y * e1z - e3z * e1y;
    float c31y = e3z * e1x - e3x * e1z;
    float c31z = e3x * e1y - e3y * e1x;
    float c12x = e1y * e2z - e1z * e2y;
    float c12y = e1z * e2x - e1x * e2z;
    float c12z = e1x * e2y - e1y * e2x;
    M[0] = c23x * inv; M[1] = c23y * inv; M[2] = c23z * inv;
    M[3] = c31x * inv; M[4] = c31y * inv; M[5] = c31z * inv;
    M[6] = c12x * inv; M[7] = c12y * inv; M[8] = c12z * inv;
  }
  for (int k = 0; k < 9; ++k) p.Tinv[t * 9 + k] = M[k];
  p.v0c[t * 3 + 0] = q0x; p.v0c[t * 3 + 1] = q0y; p.v0c[t * 3 + 2] = q0z;
  p.cold[t * 3 + 0] = (((q0x + q1x) + q2x) + q3x) * 0.25f;
  p.cold[t * 3 + 1] = (((q0y + q1y) + q2y) + q3y) * 0.25f;
  p.cold[t * 3 + 2] = (((q0z + q1z) + q2z) + q3z) * 0.25f;
  p.oel[t] = min_edge(p.verts, i0, i1, i2, i3);
}

__global__ void k_new_setup(P p){
  int n = blockIdx.x * blockDim.x + threadIdx.x;
  if (n >= TNEW) return;
  int is64 = detect64(p.rawNew);
  int i0 = ld_idx(p.rawNew, is64, n * 4 + 0);
  int i1 = ld_idx(p.rawNew, is64, n * 4 + 1);
  int i2 = ld_idx(p.rawNew, is64, n * 4 + 2);
  int i3 = ld_idx(p.rawNew, is64, n * 4 + 3);
  p.idxNew[n * 4 + 0] = i0; p.idxNew[n * 4 + 1] = i1;
  p.idxNew[n * 4 + 2] = i2; p.idxNew[n * 4 + 3] = i3;
  int s0 = i0, s1 = i1, s2 = i2, s3 = i3;
  cswap(s0, s1); cswap(s2, s3); cswap(s0, s2); cswap(s1, s3); cswap(s1, s2);
  unsigned long long key =
      (unsigned long long)((((long long)s0 * NVERT + s1) * NVERT + s2) * NVERT + s3);
  int m = -1;
  {
    unsigned slot = hash64(key) & (THSZ - 1);
    while (true){
      unsigned long long k = p.tkeys[slot];
      if (k == EMPTY64) break;
      if (k == key){ m = p.tvals[slot]; break; }
      slot = (slot + 1) & (THSZ - 1);
    }
  }
  p.matched[n] = m;
  float q0x = p.verts[i0 * 3 + 0], q0y = p.verts[i0 * 3 + 1], q0z = p.verts[i0 * 3 + 2];
  float q1x = p.verts[i1 * 3 + 0], q1y = p.verts[i1 * 3 + 1], q1z = p.verts[i1 * 3 + 2];
  float q2x = p.verts[i2 * 3 + 0], q2y = p.verts[i2 * 3 + 1], q2z = p.verts[i2 * 3 + 2];
  float q3x = p.verts[i3 * 3 + 0], q3y = p.verts[i3 * 3 + 1], q3z = p.verts[i3 * 3 + 2];
  p.cnew[n * 3 + 0] = (((q0x + q1x) + q2x) + q3x) * 0.25f;
  p.cnew[n * 3 + 1] = (((q0y + q1y) + q2y) + q3y) * 0.25f;
  p.cnew[n * 3 + 2] = (((q0z + q1z) + q2z) + q3z) * 0.25f;
  p.nel[n] = min_edge(p.verts, i0, i1, i2, i3);
  int pr = p.prio[i0];
  int seed = (pr >= 0) ? (pr % TOLD) : 0;
  p.cur[n] = seed;
  p.rem[n] = seed;
  if (m < 0) atomicAdd(&p.counters[0], 1);
}

// One reference while-loop body for walker n. Returns true if still active.
__device__ __forceinline__ bool walk_step(const P& p, int n){
  int c = p.cur[n];
  float rx = p.cnew[n * 3 + 0] - p.v0c[c * 3 + 0];
  float ry = p.cnew[n * 3 + 1] - p.v0c[c * 3 + 1];
  float rz = p.cnew[n * 3 + 2] - p.v0c[c * 3 + 2];
  const float* M = &p.Tinv[c * 9];
  float b0 = M[0] * rx + M[1] * ry + M[2] * rz;
  float b1 = M[3] * rx + M[4] * ry + M[5] * rz;
  float b2 = M[6] * rx + M[7] * ry + M[8] * rz;
  float a0 = 1.0f - (b0 + b1 + b2);
  float ab[4] = {a0, b0, b1, b2};
  int amin = 0; float mn = ab[0];
  for (int j = 1; j < 4; ++j){ if (ab[j] < mn){ mn = ab[j]; amin = j; } }
  if (mn >= -0.0001f){ p.rem[n] = c; return false; }                 // converged
  int nb = p.degen[c] ? -1 : p.nbr[c * 4 + amin];                    // row-cleared if degen
  if (nb < 0){ p.rem[n] = c; return false; }                         // boundary
  p.cur[n] = nb;
  return true;
}

__global__ void k_walk1(P p){
  int n = blockIdx.x * blockDim.x + threadIdx.x;
  if (n >= TNEW) return;
  if (p.matched[n] >= 0) return;
  int nw = p.counters[0];
  // reference loop runs at all iff n_walk >= max(100, n_walk/1000) <=> n_walk >= 100
  if (nw < 100){
    int pos = atomicAdd(&p.counters[1], 1);
    p.listA[pos] = n;                  // unstepped; goes straight to fallback
    return;
  }
  if (walk_step(p, n)){
    int pos = atomicAdd(&p.counters[1], 1);
    p.listA[pos] = n;
  }
}

__global__ void __launch_bounds__(1024) k_persist(P p){
  __shared__ int s_cnt;
  int thr = max(100, p.counters[0] / 1000);
  if (threadIdx.x == 0) s_cnt = atomicAdd(&p.counters[1], 0);
  __syncthreads();
  int count = s_cnt;
  int use_a = 1;
  int step = 1;                        // k_walk1 performed body #1 (if it ran)
  while (step < MAXSTEPS && count >= thr){
    int* curL = use_a ? p.listA : p.listB;
    int* nxtL = use_a ? p.listB : p.listA;
    int* nxtC = use_a ? &p.counters[2] : &p.counters[1];
    int* curC = use_a ? &p.counters[1] : &p.counters[2];
    for (int i = threadIdx.x; i < count; i += blockDim.x){
      int n = curL[i];
      if (walk_step(p, n)){
        int pos = atomicAdd(nxtC, 1);
        nxtL[pos] = n;
      }
    }
    __syncthreads();
    if (threadIdx.x == 0){
      s_cnt = atomicAdd(nxtC, 0);
      atomicExch(curC, 0);
    }
    __syncthreads();
    count = s_cnt;
    use_a ^= 1;
    ++step;
  }
  if (threadIdx.x == 0){
    p.counters[4] = count;             // final still-active count
    p.counters[5] = use_a ? 0 : 1;     // which list holds them (0=A, 1=B)
  }
}

// Nearest-old-centroid fallback, only for walkers in the final active list
// (normally empty -> one counter read and exit). Reference tie-break (strict <
// across chunks, argmin within chunk) == first index of the global float min.
__global__ void k_fallback(P p){
  __shared__ float sd[256];
  __shared__ int si[256];
  int fc = p.counters[4];
  const int* lst = p.counters[5] ? p.listB : p.listA;
  for (int e = blockIdx.x; e < fc; e += gridDim.x){
    int n = lst[e];
    float cx = p.cnew[n * 3 + 0], cy = p.cnew[n * 3 + 1], cz = p.cnew[n * 3 + 2];
    float p2 = (cx * cx + cy * cy) + cz * cz;
    float bd = 3.402823466e+38f; int bi = 0;
    for (int j = threadIdx.x; j < TOLD; j += 256){
      float ox = p.cold[j * 3 + 0], oy = p.cold[j * 3 + 1], oz = p.cold[j * 3 + 2];
      float dot = (cx * ox + cy * oy) + cz * oz;
      float c2 = (ox * ox + oy * oy) + oz * oz;
      float d = (p2 - 2.0f * dot) + c2;
      if (d < bd || (d == bd && j < bi)){ bd = d; bi = j; }
    }
    sd[threadIdx.x] = bd; si[threadIdx.x] = bi;
    __syncthreads();
    for (int s = 128; s > 0; s >>= 1){
      if ((int)threadIdx.x < s){
        float od = sd[threadIdx.x + s]; int oi = si[threadIdx.x + s];
        if (od < sd[threadIdx.x] || (od == sd[threadIdx.x] && oi < si[threadIdx.x])){
          sd[threadIdx.x] = od; si[threadIdx.x] = oi;
        }
      }
      __syncthreads();
    }
    if (threadIdx.x == 0){
      int r = si[0];
      if (r < 0) r = 0; if (r > TOLD - 1) r = TOLD - 1;
      p.rem[n] = r;
    }
    __syncthreads();
  }
}

__global__ void k_assemble(P p){
  int n = blockIdx.x * blockDim.x + threadIdx.x;
  if (n >= TNEW) return;
  int m = p.matched[n];
  int remap = (m >= 0) ? m : p.rem[n];
  int cds[5];
  cds[0] = remap;
  int dg = p.degen[remap];
  for (int l = 0; l < 4; ++l){
    int fb = dg ? -1 : p.nbr[remap * 4 + l];
    cds[1 + l] = (fb >= 0) ? fb : remap;
  }
  if (m >= 0){ for (int c = 0; c < 5; ++c) cds[c] = m; }
  int ni0 = p.idxNew[n * 4 + 0], ni1 = p.idxNew[n * 4 + 1];
  int ni2 = p.idxNew[n * 4 + 2], ni3 = p.idxNew[n * 4 + 3];
  float nc0 = p.ncc[n * 3 + 0], nc1 = p.ncc[n * 3 + 1], nc2 = p.ncc[n * 3 + 2];
  float raws[5]; float rsum = 0.0f;
  for (int c = 0; c < 5; ++c){
    int ct = cds[c];
    int ov = 0;
    for (int k = 0; k < 4; ++k){
      int cv = p.idxOld[ct * 4 + k];
      ov += (cv == ni0 || cv == ni1 || cv == ni2 || cv == ni3) ? 1 : 0;
    }
    float d0 = p.occ[ct * 3 + 0] - nc0;
    float d1 = p.occ[ct * 3 + 1] - nc1;
    float d2 = p.occ[ct * 3 + 2] - nc2;
    float ccd2 = (d0 * d0 + d1 * d1) + d2 * d2;
    float raw = expf((float)ov * 2.0f) / (ccd2 + 1e-8f);
    raws[c] = raw; rsum += raw;
  }
  float nelv = fmaxf(p.nel[n], 1e-8f);
  for (int c = 0; c < 5; ++c){
    p.out[n * 5 + c] = (float)cds[c];
    p.out[TNEW * 5 + n * 5 + c] = raws[c] / rsum;
    float ds = p.oel[cds[c]] / nelv;
    ds = fminf(fmaxf(ds, 0.1f), 10.0f);
    p.out[2 * TNEW * 5 + n * 5 + c] = ds;
  }
}

extern "C" void kernel_launch(void* const* d_in, const int* in_sizes, int n_in,
                              void* d_out, int out_size, void* d_ws, size_t ws_size,
                              hipStream_t stream) {
  char* w = (char*)d_ws;
  P p;
  p.rawNew = (const unsigned int*)d_in[0];
  p.rawOld = (const unsigned int*)d_in[1];
  p.occ    = (const float*)d_in[2];
  p.ncc    = (const float*)d_in[3];
  p.verts  = (const float*)d_in[4];
  p.out    = (float*)d_out;
  p.tkeys    = (unsigned long long*)(w + OFF_TKEYS);
  p.ftab     = (unsigned long long*)(w + OFF_FTAB);
  p.tvals    = (int*)(w + OFF_TVALS);
  p.nbr      = (int*)(w + OFF_NBR);
  p.prio     = (int*)(w + OFF_PRIO);
  p.counters = (int*)(w + OFF_CNT);
  p.idxNew   = (int*)(w + OFF_IDXNEW);
  p.idxOld   = (int*)(w + OFF_IDXOLD);
  p.matched  = (int*)(w + OFF_MATCHED);
  p.cur      = (int*)(w + OFF_CUR);
  p.rem      = (int*)(w + OFF_REM);
  p.degen    = (int*)(w + OFF_DEGEN);
  p.listA    = (int*)(w + OFF_LISTA);
  p.listB    = (int*)(w + OFF_LISTB);
  p.Tinv     = (float*)(w + OFF_TINV);
  p.v0c      = (float*)(w + OFF_V0C);
  p.cold     = (float*)(w + OFF_COLD);
  p.oel      = (float*)(w + OFF_OEL);
  p.cnew     = (float*)(w + OFF_CNEW);
  p.nel      = (float*)(w + OFF_NEL);

  // table init via DMA memset instead of a kernel: tkeys/ftab/tvals/nbr/prio
  // are contiguous and all want 0xFF (-1 / EMPTY64); counters want 0.
  hipMemsetAsync(w, 0xFF, FF_BYTES, stream);
  hipMemsetAsync(w + OFF_CNT, 0, 256, stream);

  dim3 B(256);
  hipLaunchKernelGGL(k_old_setup, dim3((TOLD + 255) / 256), B, 0, stream, p);
  hipLaunchKernelGGL(k_new_setup, dim3((TNEW + 255) / 256), B, 0, stream, p);
  hipLaunchKernelGGL(k_walk1,     dim3((TNEW + 255) / 256), B, 0, stream, p);
  hipLaunchKernelGGL(k_persist,   dim3(1), dim3(1024), 0, stream, p);
  hipLaunchKernelGGL(k_fallback,  dim3(120), B, 0, stream, p);
  hipLaunchKernelGGL(k_assemble,  dim3((TNEW + 255) / 256), B, 0, stream, p);
}

// Round 3
// 147.660 us; speedup vs baseline: 1.4138x; 1.0399x over previous
//
#include <hip/hip_runtime.h>

#pragma clang fp contract(off)

#define TOLD 60000
#define TNEW 60000
#define NVERT 30000
#define MAXSTEPS 300
#define THSZ 131072                  // tet-key hash slots (load 0.46)
#define FHSZ 524288                  // face-key hash slots (load 0.46)
#define EMPTY64 0xFFFFFFFFFFFFFFFFULL

// workspace layout: [0xFF-init region][rest]
#define OFF_TKEYS    0u              // 131072*8 = 1,048,576
#define OFF_FTAB     1048576u        // 524288*8 = 4,194,304
#define OFF_TVALS    5242880u        // 131072*4 = 524,288
#define OFF_NBR      5767168u        // 240000*4 = 960,000
#define OFF_PRIO     6727168u        // 30000*4  = 120,000
#define FF_BYTES     6847168u        // end of 0xFF region
#define OFF_CNT      6847168u        // 256 B (zeroed by k_old_geom)
#define OFF_IDXNEW   6847424u        // 960,000 (16B aligned)
#define OFF_IDXOLD   7807424u        // 960,000
#define OFF_MATCHED  8767424u        // 240,000
#define OFF_CUR      9007424u        // 240,000
#define OFF_REM      9247424u        // 240,000
#define OFF_DEGEN    9487424u        // 240,000
#define OFF_LISTA    9727424u        // 240,000
#define OFF_LISTB    9967424u        // 240,000
#define OFF_TV4      10207424u       // 60000*48 = 2,880,000 (3 float4/tet: M row + v0 comp)
#define OFF_COLD4    13087424u       // 60000*16 =   960,000 (cold.xyz, oel in w)
#define OFF_CNEW4    14047424u       // 60000*16 =   960,000 (cnew.xyz, nel in w)
                                     // total 15,007,424 B

struct P {
  const unsigned int* rawNew;        // new_indices raw (int32 or int64, detected)
  const unsigned int* rawOld;        // old_indices raw
  const float* occ;                  // old_cc  (TOLD,3)
  const float* ncc;                  // new_cc  (TNEW,3)
  const float* verts;                // vertex_positions (NVERT,3)
  float* out;                        // cands | weights | density, each (TNEW,5) flat
  unsigned long long* tkeys;         // tet hash keys
  unsigned long long* ftab;          // face hash (key<<18 | tet*4+local)
  int* counters;                     // [0]=n_walk [1]=cntA [2]=cntB [4]=finalCnt [5]=finalList
  int* tvals;                        // tet hash values (max tet id)
  int* idxNew; int* idxOld;          // int32-normalized indices
  int* nbr;                          // neighbors (TOLD,4), -1 = none
  int* prio;                         // per-vertex max(vi*TOLD+t)
  int* matched;                      // per new tet: old tet id or -1
  int* cur; int* rem;                // walk state
  int* degen;                        // per old tet degenerate flag
  int* listA; int* listB;            // active-list ping-pong
  float4* Tv4;                       // (TOLD,3) rows: (M[3k..3k+2], v0[k])
  float4* cold4;                     // (TOLD)   (centroid, min-edge)
  float4* cnew4;                     // (TNEW)   (centroid, min-edge)
};

__device__ __forceinline__ unsigned hash64(unsigned long long k){
  k ^= k >> 33; k *= 0xff51afd7ed558ccdULL;
  k ^= k >> 33; k *= 0xc4ceb9fe1a85ec53ULL;
  k ^= k >> 33;
  return (unsigned)k;
}
__device__ __forceinline__ void cswap(int& a, int& b){ if (a > b){ int t = a; a = b; b = t; } }

// int64 buffers (values in [0,2^31)) have zero high words at odd u32 positions;
// int32 buffers have col1 >= 1 at flat position 1. Uniform addresses -> the
// compiler scalarizes these to s_load; cost is negligible.
__device__ __forceinline__ int detect64(const unsigned int* raw){
  unsigned acc = 0;
  const uint4* r4 = (const uint4*)raw;
  #pragma unroll
  for (int k = 0; k < 32; ++k){ uint4 v = r4[k]; acc |= (v.y | v.w); }
  return acc == 0u;
}
__device__ __forceinline__ int ld_idx(const unsigned int* raw, int is64, int i){
  return is64 ? (int)((const long long*)raw)[i] : ((const int*)raw)[i];
}

__device__ __forceinline__ void face_insert(unsigned long long* ftab, int* nbr,
                                            unsigned long long fkey, int t, int l){
  unsigned long long mine = (fkey << 18) | (unsigned long long)(t * 4 + l);
  unsigned slot = hash64(fkey) & (FHSZ - 1);
  while (true){
    unsigned long long prev = atomicCAS(&ftab[slot], EMPTY64, mine);
    if (prev == EMPTY64) return;                       // first holder of this face
    if ((prev >> 18) == fkey){                         // partner: link both ways
      int oid = (int)(prev & 0x3FFFFULL);
      nbr[t * 4 + l] = oid >> 2;
      nbr[oid] = t;
      return;
    }
    slot = (slot + 1) & (FHSZ - 1);
  }
}

__device__ __forceinline__ float min_edge(const float* __restrict__ verts,
                                          int i0, int i1, int i2, int i3){
  float q[4][3];
  int iv[4] = {i0, i1, i2, i3};
  for (int k = 0; k < 4; ++k){
    q[k][0] = verts[iv[k] * 3 + 0];
    q[k][1] = verts[iv[k] * 3 + 1];
    q[k][2] = verts[iv[k] * 3 + 2];
  }
  const int ea[6] = {0, 0, 0, 1, 1, 2};
  const int eb[6] = {1, 2, 3, 2, 3, 3};
  float m = 3.402823466e+38f;
  for (int e = 0; e < 6; ++e){
    float dx = q[ea[e]][0] - q[eb[e]][0];
    float dy = q[ea[e]][1] - q[eb[e]][1];
    float dz = q[ea[e]][2] - q[eb[e]][2];
    float d = sqrtf((dx * dx + dy * dy) + dz * dz);
    m = fminf(m, d);
  }
  return m;
}

// Streaming geometry pass: no atomics. Also zeroes the counter block (runs
// strictly before any counter consumer).
__global__ void k_old_geom(P p){
  int t = blockIdx.x * blockDim.x + threadIdx.x;
  if (blockIdx.x == 0 && threadIdx.x < 64) p.counters[threadIdx.x] = 0;
  if (t >= TOLD) return;
  int is64 = detect64(p.rawOld);
  int i0 = ld_idx(p.rawOld, is64, t * 4 + 0);
  int i1 = ld_idx(p.rawOld, is64, t * 4 + 1);
  int i2 = ld_idx(p.rawOld, is64, t * 4 + 2);
  int i3 = ld_idx(p.rawOld, is64, t * 4 + 3);
  ((int4*)p.idxOld)[t] = make_int4(i0, i1, i2, i3);

  float q0x = p.verts[i0 * 3 + 0], q0y = p.verts[i0 * 3 + 1], q0z = p.verts[i0 * 3 + 2];
  float q1x = p.verts[i1 * 3 + 0], q1y = p.verts[i1 * 3 + 1], q1z = p.verts[i1 * 3 + 2];
  float q2x = p.verts[i2 * 3 + 0], q2y = p.verts[i2 * 3 + 1], q2z = p.verts[i2 * 3 + 2];
  float q3x = p.verts[i3 * 3 + 0], q3y = p.verts[i3 * 3 + 1], q3z = p.verts[i3 * 3 + 2];
  float e1x = q1x - q0x, e1y = q1y - q0y, e1z = q1z - q0z;
  float e2x = q2x - q0x, e2y = q2y - q0y, e2z = q2z - q0z;
  float e3x = q3x - q0x, e3y = q3y - q0y, e3z = q3z - q0z;
  float c23x = e2y * e3z - e2z * e3y;
  float c23y = e2z * e3x - e2x * e3z;
  float c23z = e2x * e3y - e2y * e3x;
  float det = e1x * c23x + e1y * c23y + e1z * c23z;
  int dg = (fabsf(det) < 1e-10f) ? 1 : 0;
  p.degen[t] = dg;
  float4 r0, r1, r2;
  if (dg){
    r0 = make_float4(1.f, 0.f, 0.f, q0x);
    r1 = make_float4(0.f, 1.f, 0.f, q0y);
    r2 = make_float4(0.f, 0.f, 1.f, q0z);
  } else {
    float inv = 1.0f / det;
    float c31x = e3y * e1z - e3z * e1y;
    float c31y = e3z * e1x - e3x * e1z;
    float c31z = e3x * e1y - e3y * e1x;
    float c12x = e1y * e2z - e1z * e2y;
    float c12y = e1z * e2x - e1x * e2z;
    float c12z = e1x * e2y - e1y * e2x;
    r0 = make_float4(c23x * inv, c23y * inv, c23z * inv, q0x);
    r1 = make_float4(c31x * inv, c31y * inv, c31z * inv, q0y);
    r2 = make_float4(c12x * inv, c12y * inv, c12z * inv, q0z);
  }
  p.Tv4[t * 3 + 0] = r0;
  p.Tv4[t * 3 + 1] = r1;
  p.Tv4[t * 3 + 2] = r2;
  float el = min_edge(p.verts, i0, i1, i2, i3);
  p.cold4[t] = make_float4((((q0x + q1x) + q2x) + q3x) * 0.25f,
                           (((q0y + q1y) + q2y) + q3y) * 0.25f,
                           (((q0z + q1z) + q2z) + q3z) * 0.25f, el);
}

// Atomic pass: one thread per (tet, local face). Each thread: 1 face-CAS +
// 1 prio-max; lane l==0 additionally does the tet-key CAS + tvals-max.
// 240k threads -> 4x the waves of the fused version, ~3 atomics/thread max.
__global__ void k_old_hash(P p){
  int i = blockIdx.x * blockDim.x + threadIdx.x;
  if (i >= TOLD * 4) return;
  int t = i >> 2, l = i & 3;
  int is64 = detect64(p.rawOld);
  int iv[4];
  iv[0] = ld_idx(p.rawOld, is64, t * 4 + 0);
  iv[1] = ld_idx(p.rawOld, is64, t * 4 + 1);
  iv[2] = ld_idx(p.rawOld, is64, t * 4 + 2);
  iv[3] = ld_idx(p.rawOld, is64, t * 4 + 3);

  atomicMax(&p.prio[iv[l]], l * TOLD + t);

  if (l == 0){
    int s0 = iv[0], s1 = iv[1], s2 = iv[2], s3 = iv[3];
    cswap(s0, s1); cswap(s2, s3); cswap(s0, s2); cswap(s1, s3); cswap(s1, s2);
    unsigned long long key =
        (unsigned long long)((((long long)s0 * NVERT + s1) * NVERT + s2) * NVERT + s3);
    unsigned slot = hash64(key) & (THSZ - 1);
    while (true){
      unsigned long long prev = atomicCAS(&p.tkeys[slot], EMPTY64, key);
      if (prev == EMPTY64 || prev == key){ atomicMax(&p.tvals[slot], t); break; }
      slot = (slot + 1) & (THSZ - 1);
    }
  }

  const int FO[4][3] = {{1, 2, 3}, {0, 2, 3}, {0, 1, 3}, {0, 1, 2}};
  int a = iv[FO[l][0]], b = iv[FO[l][1]], c = iv[FO[l][2]];
  cswap(a, b); cswap(a, c); cswap(b, c);
  unsigned long long fk = (unsigned long long)(((long long)a * NVERT + b) * NVERT + c);
  face_insert(p.ftab, p.nbr, fk, t, l);
}

__global__ void k_new_setup(P p){
  int n = blockIdx.x * blockDim.x + threadIdx.x;
  if (n >= TNEW) return;
  int is64 = detect64(p.rawNew);
  int i0 = ld_idx(p.rawNew, is64, n * 4 + 0);
  int i1 = ld_idx(p.rawNew, is64, n * 4 + 1);
  int i2 = ld_idx(p.rawNew, is64, n * 4 + 2);
  int i3 = ld_idx(p.rawNew, is64, n * 4 + 3);
  ((int4*)p.idxNew)[n] = make_int4(i0, i1, i2, i3);
  int s0 = i0, s1 = i1, s2 = i2, s3 = i3;
  cswap(s0, s1); cswap(s2, s3); cswap(s0, s2); cswap(s1, s3); cswap(s1, s2);
  unsigned long long key =
      (unsigned long long)((((long long)s0 * NVERT + s1) * NVERT + s2) * NVERT + s3);
  int m = -1;
  {
    unsigned slot = hash64(key) & (THSZ - 1);
    while (true){
      unsigned long long k = p.tkeys[slot];
      if (k == EMPTY64) break;
      if (k == key){ m = p.tvals[slot]; break; }
      slot = (slot + 1) & (THSZ - 1);
    }
  }
  p.matched[n] = m;
  float q0x = p.verts[i0 * 3 + 0], q0y = p.verts[i0 * 3 + 1], q0z = p.verts[i0 * 3 + 2];
  float q1x = p.verts[i1 * 3 + 0], q1y = p.verts[i1 * 3 + 1], q1z = p.verts[i1 * 3 + 2];
  float q2x = p.verts[i2 * 3 + 0], q2y = p.verts[i2 * 3 + 1], q2z = p.verts[i2 * 3 + 2];
  float q3x = p.verts[i3 * 3 + 0], q3y = p.verts[i3 * 3 + 1], q3z = p.verts[i3 * 3 + 2];
  float el = min_edge(p.verts, i0, i1, i2, i3);
  p.cnew4[n] = make_float4((((q0x + q1x) + q2x) + q3x) * 0.25f,
                           (((q0y + q1y) + q2y) + q3y) * 0.25f,
                           (((q0z + q1z) + q2z) + q3z) * 0.25f, el);
  int pr = p.prio[i0];
  int seed = (pr >= 0) ? (pr % TOLD) : 0;
  p.cur[n] = seed;
  p.rem[n] = seed;
  if (m < 0) atomicAdd(&p.counters[0], 1);
}

// One reference while-loop body for walker n. Returns true if still active.
__device__ __forceinline__ bool walk_step(const P& p, int n){
  int c = p.cur[n];
  float4 r0 = p.Tv4[c * 3 + 0];
  float4 r1 = p.Tv4[c * 3 + 1];
  float4 r2 = p.Tv4[c * 3 + 2];
  float4 cn = p.cnew4[n];
  float rx = cn.x - r0.w, ry = cn.y - r1.w, rz = cn.z - r2.w;
  float b0 = r0.x * rx + r0.y * ry + r0.z * rz;
  float b1 = r1.x * rx + r1.y * ry + r1.z * rz;
  float b2 = r2.x * rx + r2.y * ry + r2.z * rz;
  float a0 = 1.0f - (b0 + b1 + b2);
  float ab[4] = {a0, b0, b1, b2};
  int amin = 0; float mn = ab[0];
  for (int j = 1; j < 4; ++j){ if (ab[j] < mn){ mn = ab[j]; amin = j; } }
  if (mn >= -0.0001f){ p.rem[n] = c; return false; }                 // converged
  int nb = p.degen[c] ? -1 : p.nbr[c * 4 + amin];                    // row-cleared if degen
  if (nb < 0){ p.rem[n] = c; return false; }                         // boundary
  p.cur[n] = nb;
  return true;
}

__global__ void k_walk1(P p){
  int n = blockIdx.x * blockDim.x + threadIdx.x;
  if (n >= TNEW) return;
  if (p.matched[n] >= 0) return;
  int nw = p.counters[0];
  // reference loop runs at all iff n_walk >= max(100, n_walk/1000) <=> n_walk >= 100
  if (nw < 100){
    int pos = atomicAdd(&p.counters[1], 1);
    p.listA[pos] = n;                  // unstepped; goes straight to fallback
    return;
  }
  if (walk_step(p, n)){
    int pos = atomicAdd(&p.counters[1], 1);
    p.listA[pos] = n;
  }
}

__global__ void __launch_bounds__(1024) k_persist(P p){
  __shared__ int s_cnt;
  int thr = max(100, p.counters[0] / 1000);
  if (threadIdx.x == 0) s_cnt = atomicAdd(&p.counters[1], 0);
  __syncthreads();
  int count = s_cnt;
  int use_a = 1;
  int step = 1;                        // k_walk1 performed body #1 (if it ran)
  while (step < MAXSTEPS && count >= thr){
    int* curL = use_a ? p.listA : p.listB;
    int* nxtL = use_a ? p.listB : p.listA;
    int* nxtC = use_a ? &p.counters[2] : &p.counters[1];
    int* curC = use_a ? &p.counters[1] : &p.counters[2];
    for (int i = threadIdx.x; i < count; i += blockDim.x){
      int n = curL[i];
      if (walk_step(p, n)){
        int pos = atomicAdd(nxtC, 1);
        nxtL[pos] = n;
      }
    }
    __syncthreads();
    if (threadIdx.x == 0){
      s_cnt = atomicAdd(nxtC, 0);
      atomicExch(curC, 0);
    }
    __syncthreads();
    count = s_cnt;
    use_a ^= 1;
    ++step;
  }
  if (threadIdx.x == 0){
    p.counters[4] = count;             // final still-active count
    p.counters[5] = use_a ? 0 : 1;     // which list holds them (0=A, 1=B)
  }
}

// Nearest-old-centroid fallback, only for walkers in the final active list.
// Reference tie-break (strict < across chunks, argmin within chunk) == first
// index of the global float min.
__global__ void k_fallback(P p){
  __shared__ float sd[256];
  __shared__ int si[256];
  int fc = p.counters[4];
  const int* lst = p.counters[5] ? p.listB : p.listA;
  for (int e = blockIdx.x; e < fc; e += gridDim.x){
    int n = lst[e];
    float4 cn = p.cnew4[n];
    float cx = cn.x, cy = cn.y, cz = cn.z;
    float p2 = (cx * cx + cy * cy) + cz * cz;
    float bd = 3.402823466e+38f; int bi = 0;
    for (int j = threadIdx.x; j < TOLD; j += 256){
      float4 oc = p.cold4[j];
      float dot = (cx * oc.x + cy * oc.y) + cz * oc.z;
      float c2 = (oc.x * oc.x + oc.y * oc.y) + oc.z * oc.z;
      float d = (p2 - 2.0f * dot) + c2;
      if (d < bd || (d == bd && j < bi)){ bd = d; bi = j; }
    }
    sd[threadIdx.x] = bd; si[threadIdx.x] = bi;
    __syncthreads();
    for (int s = 128; s > 0; s >>= 1){
      if ((int)threadIdx.x < s){
        float od = sd[threadIdx.x + s]; int oi = si[threadIdx.x + s];
        if (od < sd[threadIdx.x] || (od == sd[threadIdx.x] && oi < si[threadIdx.x])){
          sd[threadIdx.x] = od; si[threadIdx.x] = oi;
        }
      }
      __syncthreads();
    }
    if (threadIdx.x == 0){
      int r = si[0];
      if (r < 0) r = 0; if (r > TOLD - 1) r = TOLD - 1;
      p.rem[n] = r;
    }
    __syncthreads();
  }
}

__global__ void k_assemble(P p){
  int n = blockIdx.x * blockDim.x + threadIdx.x;
  if (n >= TNEW) return;
  int m = p.matched[n];
  int remap = (m >= 0) ? m : p.rem[n];
  int cds[5];
  cds[0] = remap;
  int dg = p.degen[remap];
  for (int l = 0; l < 4; ++l){
    int fb = dg ? -1 : p.nbr[remap * 4 + l];
    cds[1 + l] = (fb >= 0) ? fb : remap;
  }
  if (m >= 0){ for (int c = 0; c < 5; ++c) cds[c] = m; }
  int4 ni = ((const int4*)p.idxNew)[n];
  float nc0 = p.ncc[n * 3 + 0], nc1 = p.ncc[n * 3 + 1], nc2 = p.ncc[n * 3 + 2];
  float raws[5]; float rsum = 0.0f;
  float oels[5];
  for (int c = 0; c < 5; ++c){
    int ct = cds[c];
    int4 cv = ((const int4*)p.idxOld)[ct];
    int ov = 0;
    ov += (cv.x == ni.x || cv.x == ni.y || cv.x == ni.z || cv.x == ni.w) ? 1 : 0;
    ov += (cv.y == ni.x || cv.y == ni.y || cv.y == ni.z || cv.y == ni.w) ? 1 : 0;
    ov += (cv.z == ni.x || cv.z == ni.y || cv.z == ni.z || cv.z == ni.w) ? 1 : 0;
    ov += (cv.w == ni.x || cv.w == ni.y || cv.w == ni.z || cv.w == ni.w) ? 1 : 0;
    float d0 = p.occ[ct * 3 + 0] - nc0;
    float d1 = p.occ[ct * 3 + 1] - nc1;
    float d2 = p.occ[ct * 3 + 2] - nc2;
    float ccd2 = (d0 * d0 + d1 * d1) + d2 * d2;
    float raw = expf((float)ov * 2.0f) / (ccd2 + 1e-8f);
    raws[c] = raw; rsum += raw;
    oels[c] = p.cold4[ct].w;
  }
  float nelv = fmaxf(p.cnew4[n].w, 1e-8f);
  for (int c = 0; c < 5; ++c){
    p.out[n * 5 + c] = (float)cds[c];
    p.out[TNEW * 5 + n * 5 + c] = raws[c] / rsum;
    float ds = oels[c] / nelv;
    ds = fminf(fmaxf(ds, 0.1f), 10.0f);
    p.out[2 * TNEW * 5 + n * 5 + c] = ds;
  }
}

extern "C" void kernel_launch(void* const* d_in, const int* in_sizes, int n_in,
                              void* d_out, int out_size, void* d_ws, size_t ws_size,
                              hipStream_t stream) {
  char* w = (char*)d_ws;
  P p;
  p.rawNew = (const unsigned int*)d_in[0];
  p.rawOld = (const unsigned int*)d_in[1];
  p.occ    = (const float*)d_in[2];
  p.ncc    = (const float*)d_in[3];
  p.verts  = (const float*)d_in[4];
  p.out    = (float*)d_out;
  p.tkeys    = (unsigned long long*)(w + OFF_TKEYS);
  p.ftab     = (unsigned long long*)(w + OFF_FTAB);
  p.tvals    = (int*)(w + OFF_TVALS);
  p.nbr      = (int*)(w + OFF_NBR);
  p.prio     = (int*)(w + OFF_PRIO);
  p.counters = (int*)(w + OFF_CNT);
  p.idxNew   = (int*)(w + OFF_IDXNEW);
  p.idxOld   = (int*)(w + OFF_IDXOLD);
  p.matched  = (int*)(w + OFF_MATCHED);
  p.cur      = (int*)(w + OFF_CUR);
  p.rem      = (int*)(w + OFF_REM);
  p.degen    = (int*)(w + OFF_DEGEN);
  p.listA    = (int*)(w + OFF_LISTA);
  p.listB    = (int*)(w + OFF_LISTB);
  p.Tv4      = (float4*)(w + OFF_TV4);
  p.cold4    = (float4*)(w + OFF_COLD4);
  p.cnew4    = (float4*)(w + OFF_CNEW4);

  // tkeys/ftab/tvals/nbr/prio are contiguous and all want 0xFF (-1 / EMPTY64)
  hipMemsetAsync(w, 0xFF, FF_BYTES, stream);

  dim3 B(256);
  hipLaunchKernelGGL(k_old_geom, dim3((TOLD + 255) / 256), B, 0, stream, p);
  hipLaunchKernelGGL(k_old_hash, dim3((TOLD * 4 + 255) / 256), B, 0, stream, p);
  hipLaunchKernelGGL(k_new_setup, dim3((TNEW + 255) / 256), B, 0, stream, p);
  hipLaunchKernelGGL(k_walk1,     dim3((TNEW + 255) / 256), B, 0, stream, p);
  hipLaunchKernelGGL(k_persist,   dim3(1), dim3(1024), 0, stream, p);
  hipLaunchKernelGGL(k_fallback,  dim3(120), B, 0, stream, p);
  hipLaunchKernelGGL(k_assemble,  dim3((TNEW + 255) / 256), B, 0, stream, p);
}